// Round 1
// baseline (320.270 us; speedup 1.0000x reference)
//
#include <hip/hip_runtime.h>
#include <hip/hip_bf16.h>

#define GN 4096
#define CAP 512
#define NGRAPH 64

// ---------------- CSR build: one block per row, append nonzero cols ----------
__global__ __launch_bounds__(256) void build_csr(
    const float* __restrict__ adj, int* __restrict__ cnt_, int* __restrict__ col_)
{
    __shared__ int lcnt;
    int i = blockIdx.x;
    if (threadIdx.x == 0) lcnt = 0;
    __syncthreads();
    const float* row = adj + (size_t)i * GN;
    int* cols = col_ + (size_t)i * CAP;
    for (int j = threadIdx.x * 4; j < GN; j += 1024) {
        float4 v = *(const float4*)(row + j);
        if (v.x != 0.f) { int p = atomicAdd(&lcnt, 1); if (p < CAP) cols[p] = j + 0; }
        if (v.y != 0.f) { int p = atomicAdd(&lcnt, 1); if (p < CAP) cols[p] = j + 1; }
        if (v.z != 0.f) { int p = atomicAdd(&lcnt, 1); if (p < CAP) cols[p] = j + 2; }
        if (v.w != 0.f) { int p = atomicAdd(&lcnt, 1); if (p < CAP) cols[p] = j + 3; }
    }
    __syncthreads();
    if (threadIdx.x == 0) cnt_[i] = lcnt < CAP ? lcnt : CAP;
}

// ---------------- Linear: F[N,64] = A[N,KDIM] @ Wcat + bias -----------------
// W layout: [2][KDIM][32]; col c -> head c>>5, feat c&31.
template<int KDIM>
__global__ __launch_bounds__(256) void linear_kernel(
    const float* __restrict__ A, int lda,
    const float* __restrict__ W, const float* __restrict__ bias,
    float* __restrict__ F)
{
    __shared__ float As[16][68];
    __shared__ float Bs[16][68];
    int i0 = blockIdx.x * 64;
    int t = threadIdx.x;
    int tx = t & 15, ty = t >> 4;
    float acc[4][4] = {};
    for (int kc = 0; kc < KDIM; kc += 16) {
#pragma unroll
        for (int p = 0; p < 4; ++p) {
            int q = t + p * 256;
            int m = q >> 4, kk = q & 15;
            As[kk][m] = A[(size_t)(i0 + m) * lda + kc + kk];
        }
#pragma unroll
        for (int p = 0; p < 4; ++p) {
            int q = t + p * 256;
            int kk = q >> 6, n = q & 63;
            Bs[kk][n] = W[(size_t)(n >> 5) * KDIM * 32 + (size_t)(kc + kk) * 32 + (n & 31)];
        }
        __syncthreads();
#pragma unroll
        for (int kk = 0; kk < 16; ++kk) {
            float a[4], b[4];
#pragma unroll
            for (int i = 0; i < 4; ++i) a[i] = As[kk][ty * 4 + i];
#pragma unroll
            for (int j = 0; j < 4; ++j) b[j] = Bs[kk][tx * 4 + j];
#pragma unroll
            for (int i = 0; i < 4; ++i)
#pragma unroll
                for (int j = 0; j < 4; ++j) acc[i][j] += a[i] * b[j];
        }
        __syncthreads();
    }
#pragma unroll
    for (int i = 0; i < 4; ++i) {
        int row = i0 + ty * 4 + i;
#pragma unroll
        for (int j = 0; j < 4; ++j) {
            int col = tx * 4 + j;
            F[(size_t)row * 64 + col] = acc[i][j] + bias[col];
        }
    }
}

// ---------------- scores: s1[k][n], s2[k][n] --------------------------------
__global__ __launch_bounds__(256) void scores_kernel(
    const float* __restrict__ f, const float* __restrict__ a1w,
    const float* __restrict__ a1b, const float* __restrict__ a2w,
    const float* __restrict__ a2b, float* __restrict__ s1, float* __restrict__ s2)
{
    int n = blockIdx.x * 256 + threadIdx.x;
    const float* fr = f + (size_t)n * 64;
#pragma unroll
    for (int k = 0; k < 2; ++k) {
        float d1 = 0.f, d2 = 0.f;
#pragma unroll
        for (int h = 0; h < 32; ++h) {
            float v = fr[k * 32 + h];
            d1 += v * a1w[k * 32 + h];
            d2 += v * a2w[k * 32 + h];
        }
        s1[k * GN + n] = d1 + a1b[k];
        s2[k * GN + n] = d2 + a2b[k];
    }
}

// ---------------- attention: one block per row, wave per head ---------------
__global__ __launch_bounds__(128) void attn_kernel(
    const float* __restrict__ f, const float* __restrict__ s1,
    const float* __restrict__ s2, const int* __restrict__ cnt_,
    const int* __restrict__ col_, float* __restrict__ xout,
    int ostride, int ocol0)
{
    __shared__ float w[2][CAP];
    int i = blockIdx.x;
    int tid = threadIdx.x;
    int k = tid >> 6, lane = tid & 63;
    int cnt = cnt_[i];
    const int* cols = col_ + (size_t)i * CAP;
    float s1i = s1[k * GN + i];
    // pass 1: leaky scores + max
    float m = -1e30f;
    for (int c = lane; c < cnt; c += 64) {
        int j = cols[c];
        float e = s1i + s2[k * GN + j];
        e = e > 0.f ? e : 0.01f * e;
        w[k][c] = e;
        m = fmaxf(m, e);
    }
#pragma unroll
    for (int off = 32; off; off >>= 1) m = fmaxf(m, __shfl_xor(m, off));
    // pass 2: exp + sum
    float s = 0.f;
    for (int c = lane; c < cnt; c += 64) {
        float v = __expf(w[k][c] - m);
        w[k][c] = v;
        s += v;
    }
#pragma unroll
    for (int off = 32; off; off >>= 1) s += __shfl_xor(s, off);
    __syncthreads();
    // phase B: weighted sum of f rows; lanes 0..31 = features, two edges in parallel
    int h = lane & 31, half = lane >> 5;
    float o = 0.f;
    for (int c = half; c < cnt; c += 2) {
        int j = cols[c];
        o += w[k][c] * f[(size_t)j * 64 + 32 * k + h];
    }
    o += __shfl_xor(o, 32);
    if (half == 0) {
        float v = o / s;
        xout[(size_t)i * ostride + ocol0 + 32 * k + h] = v > 0.f ? v : 0.f;
    }
}

// ---------------- pooling ---------------------------------------------------
__global__ void init_bounds(int* gstart, int* gend)
{
    int g = threadIdx.x;
    if (g < NGRAPH) { gstart[g] = GN; gend[g] = 0; }
}

__global__ __launch_bounds__(256) void bounds_kernel(
    const int* __restrict__ batch, int* gstart, int* gend)
{
    int n = blockIdx.x * 256 + threadIdx.x;
    int g = batch[n];
    atomicMin(&gstart[g], n);
    atomicMax(&gend[g], n + 1);
}

__global__ __launch_bounds__(192) void pool_kernel(
    const float* __restrict__ hbuf, const int* __restrict__ gstart,
    const int* __restrict__ gend, float* __restrict__ pooled)
{
    int g = blockIdx.x, t = threadIdx.x;
    int s = gstart[g], e = gend[g];
    float acc = 0.f;
    for (int n = s; n < e; ++n) acc += hbuf[(size_t)n * 192 + t];
    pooled[g * 192 + t] = (e > s) ? acc / (float)(e - s) : 0.f;
}

// ---------------- final linear + softmax ------------------------------------
__global__ __launch_bounds__(64) void final_kernel(
    const float* __restrict__ pooled, const float* __restrict__ Wf,
    const float* __restrict__ bf, float* __restrict__ out)
{
    __shared__ float z[10];
    __shared__ float red[2];
    int g = blockIdx.x, t = threadIdx.x;
    if (t < 10) {
        float acc = bf[t];
        for (int c = 0; c < 192; ++c) acc += pooled[g * 192 + c] * Wf[c * 10 + t];
        z[t] = acc;
    }
    __syncthreads();
    if (t == 0) {
        float m = z[0];
        for (int o = 1; o < 10; ++o) m = fmaxf(m, z[o]);
        float s = 0.f;
        for (int o = 0; o < 10; ++o) s += __expf(z[o] - m);
        red[0] = m; red[1] = s;
    }
    __syncthreads();
    if (t < 10) out[g * 10 + t] = __expf(z[t] - red[0]) / red[1];
}

extern "C" void kernel_launch(void* const* d_in, const int* in_sizes, int n_in,
                              void* d_out, int out_size, void* d_ws, size_t ws_size,
                              hipStream_t stream)
{
    const float* x    = (const float*)d_in[0];
    const float* adj  = (const float*)d_in[1];
    const int*   batch= (const int*)d_in[2];
    const float* W1   = (const float*)d_in[3];
    const float* b1   = (const float*)d_in[4];
    const float* a1w1 = (const float*)d_in[5];
    const float* a1b1 = (const float*)d_in[6];
    const float* a2w1 = (const float*)d_in[7];
    const float* a2b1 = (const float*)d_in[8];
    const float* W2   = (const float*)d_in[9];
    const float* b2   = (const float*)d_in[10];
    const float* a1w2 = (const float*)d_in[11];
    const float* a1b2 = (const float*)d_in[12];
    const float* a2w2 = (const float*)d_in[13];
    const float* a2b2 = (const float*)d_in[14];
    const float* W3   = (const float*)d_in[15];
    const float* b3   = (const float*)d_in[16];
    const float* a1w3 = (const float*)d_in[17];
    const float* a1b3 = (const float*)d_in[18];
    const float* a2w3 = (const float*)d_in[19];
    const float* a2b3 = (const float*)d_in[20];
    const float* Wf   = (const float*)d_in[21];
    const float* bf   = (const float*)d_in[22];
    float* out = (float*)d_out;

    char* base = (char*)d_ws;
    int*   csr_cnt = (int*)(base + 0);                    // 16384 B
    int*   gstart  = (int*)(base + 16384);                // 256 B
    int*   gend    = (int*)(base + 16640);                // 256 B
    float* s1      = (float*)(base + 17408);              // 32768 B
    float* s2      = (float*)(base + 50176);              // 32768 B
    float* fbuf    = (float*)(base + 82944);              // 4096*64*4 = 1 MiB
    float* hbuf    = (float*)(base + 1131520);            // 4096*192*4 = 3 MiB
    float* pooled  = (float*)(base + 4277248);            // 64*192*4
    int*   csr_col = (int*)(base + 4326400);              // 4096*512*4 = 8 MiB
    (void)ws_size; (void)n_in; (void)in_sizes; (void)out_size;

    build_csr<<<GN, 256, 0, stream>>>(adj, csr_cnt, csr_col);

    // layer 1
    linear_kernel<512><<<GN / 64, 256, 0, stream>>>(x, 512, W1, b1, fbuf);
    scores_kernel<<<GN / 256, 256, 0, stream>>>(fbuf, a1w1, a1b1, a2w1, a2b1, s1, s2);
    attn_kernel<<<GN, 128, 0, stream>>>(fbuf, s1, s2, csr_cnt, csr_col, hbuf, 192, 0);
    // layer 2
    linear_kernel<64><<<GN / 64, 256, 0, stream>>>(hbuf + 0, 192, W2, b2, fbuf);
    scores_kernel<<<GN / 256, 256, 0, stream>>>(fbuf, a1w2, a1b2, a2w2, a2b2, s1, s2);
    attn_kernel<<<GN, 128, 0, stream>>>(fbuf, s1, s2, csr_cnt, csr_col, hbuf, 192, 64);
    // layer 3
    linear_kernel<64><<<GN / 64, 256, 0, stream>>>(hbuf + 64, 192, W3, b3, fbuf);
    scores_kernel<<<GN / 256, 256, 0, stream>>>(fbuf, a1w3, a1b3, a2w3, a2b3, s1, s2);
    attn_kernel<<<GN, 128, 0, stream>>>(fbuf, s1, s2, csr_cnt, csr_col, hbuf, 192, 128);

    // pooling + classifier
    init_bounds<<<1, 64, 0, stream>>>(gstart, gend);
    bounds_kernel<<<GN / 256, 256, 0, stream>>>(batch, gstart, gend);
    pool_kernel<<<NGRAPH, 192, 0, stream>>>(hbuf, gstart, gend, pooled);
    final_kernel<<<NGRAPH, 64, 0, stream>>>(pooled, Wf, bf, out);
}

// Round 2
// 291.351 us; speedup vs baseline: 1.0993x; 1.0993x over previous
//
#include <hip/hip_runtime.h>
#include <hip/hip_bf16.h>

#define GN 4096
#define CAP 512
#define NGRAPH 64

// ---------------- CSR build: one block per row, append nonzero cols ----------
__global__ __launch_bounds__(256) void build_csr(
    const float* __restrict__ adj, int* __restrict__ cnt_, int* __restrict__ col_)
{
    __shared__ int lcnt;
    int i = blockIdx.x;
    if (threadIdx.x == 0) lcnt = 0;
    __syncthreads();
    const float* row = adj + (size_t)i * GN;
    int* cols = col_ + (size_t)i * CAP;
    for (int j = threadIdx.x * 4; j < GN; j += 1024) {
        float4 v = *(const float4*)(row + j);
        if (v.x != 0.f) { int p = atomicAdd(&lcnt, 1); if (p < CAP) cols[p] = j + 0; }
        if (v.y != 0.f) { int p = atomicAdd(&lcnt, 1); if (p < CAP) cols[p] = j + 1; }
        if (v.z != 0.f) { int p = atomicAdd(&lcnt, 1); if (p < CAP) cols[p] = j + 2; }
        if (v.w != 0.f) { int p = atomicAdd(&lcnt, 1); if (p < CAP) cols[p] = j + 3; }
    }
    __syncthreads();
    if (threadIdx.x == 0) cnt_[i] = lcnt < CAP ? lcnt : CAP;
}

// ------- Linear + scores fused: F = A@Wcat + bias ; s1,s2 per head ----------
// W layout: [2][KDIM][32]; col c -> head c>>5, feat c&31. bias/a1w/a2w: 64 flat.
template<int KDIM>
__global__ __launch_bounds__(256) void linear_scores(
    const float* __restrict__ A, int lda,
    const float* __restrict__ W, const float* __restrict__ bias,
    const float* __restrict__ a1w, const float* __restrict__ a1b,
    const float* __restrict__ a2w, const float* __restrict__ a2b,
    float* __restrict__ F, float* __restrict__ s1, float* __restrict__ s2)
{
    __shared__ float As[16][68];
    __shared__ float Bs[16][68];
    int i0 = blockIdx.x * 64;
    int t = threadIdx.x;
    int tx = t & 15, ty = t >> 4;
    float acc[4][4] = {};
    for (int kc = 0; kc < KDIM; kc += 16) {
        // stage A: 64 rows x 16 k, scalar coalesced (64B segments per 16 lanes)
#pragma unroll
        for (int p = 0; p < 4; ++p) {
            int q = t + p * 256;
            int m = q >> 4, kk = q & 15;
            As[kk][m] = A[(size_t)(i0 + m) * lda + kc + kk];
        }
        // stage B: 16 k x 64 cols, one float4 per thread
        {
            int kk = t >> 4, n0 = (t & 15) * 4;
            const float* wp = W + (size_t)(n0 >> 5) * KDIM * 32
                                + (size_t)(kc + kk) * 32 + (n0 & 31);
            *(float4*)&Bs[kk][n0] = *(const float4*)wp;
        }
        __syncthreads();
#pragma unroll
        for (int kk = 0; kk < 16; ++kk) {
            float4 a4 = *(const float4*)&As[kk][ty * 4];
            float4 b4 = *(const float4*)&Bs[kk][tx * 4];
            float a[4] = {a4.x, a4.y, a4.z, a4.w};
            float b[4] = {b4.x, b4.y, b4.z, b4.w};
#pragma unroll
            for (int i = 0; i < 4; ++i)
#pragma unroll
                for (int j = 0; j < 4; ++j) acc[i][j] += a[i] * b[j];
        }
        __syncthreads();
    }
    // epilogue: bias, write F (float4), fused attention scores
    int col0 = tx * 4;
    float4 bi  = *(const float4*)&bias[col0];
    float4 w1  = *(const float4*)&a1w[col0];
    float4 w2  = *(const float4*)&a2w[col0];
    int head = tx >> 3;               // cols 0..31 head0, 32..63 head1
#pragma unroll
    for (int i = 0; i < 4; ++i) {
        int row = i0 + ty * 4 + i;
        float v0 = acc[i][0] + bi.x;
        float v1 = acc[i][1] + bi.y;
        float v2 = acc[i][2] + bi.z;
        float v3 = acc[i][3] + bi.w;
        float4 v4 = {v0, v1, v2, v3};
        *(float4*)&F[(size_t)row * 64 + col0] = v4;
        float p1 = v0 * w1.x + v1 * w1.y + v2 * w1.z + v3 * w1.w;
        float p2 = v0 * w2.x + v1 * w2.y + v2 * w2.z + v3 * w2.w;
#pragma unroll
        for (int off = 1; off < 8; off <<= 1) {
            p1 += __shfl_xor(p1, off);
            p2 += __shfl_xor(p2, off);
        }
        if ((tx & 7) == 0) {
            s1[head * GN + row] = p1 + a1b[head];
            s2[head * GN + row] = p2 + a2b[head];
        }
    }
}

// ---------------- attention: one block per row, wave per head ---------------
__global__ __launch_bounds__(128) void attn_kernel(
    const float* __restrict__ f, const float* __restrict__ s1,
    const float* __restrict__ s2, const int* __restrict__ cnt_,
    const int* __restrict__ col_, float* __restrict__ xout,
    int ostride, int ocol0)
{
    __shared__ float w[2][CAP];
    int i = blockIdx.x;
    int tid = threadIdx.x;
    int k = tid >> 6, lane = tid & 63;
    int cnt = cnt_[i];
    const int* cols = col_ + (size_t)i * CAP;
    float s1i = s1[k * GN + i];
    float m = -1e30f;
    for (int c = lane; c < cnt; c += 64) {
        int j = cols[c];
        float e = s1i + s2[k * GN + j];
        e = e > 0.f ? e : 0.01f * e;
        w[k][c] = e;
        m = fmaxf(m, e);
    }
#pragma unroll
    for (int off = 32; off; off >>= 1) m = fmaxf(m, __shfl_xor(m, off));
    float s = 0.f;
    for (int c = lane; c < cnt; c += 64) {
        float v = __expf(w[k][c] - m);
        w[k][c] = v;
        s += v;
    }
#pragma unroll
    for (int off = 32; off; off >>= 1) s += __shfl_xor(s, off);
    __syncthreads();
    int h = lane & 31, half = lane >> 5;
    float o = 0.f;
    for (int c = half; c < cnt; c += 2) {
        int j = cols[c];
        o += w[k][c] * f[(size_t)j * 64 + 32 * k + h];
    }
    o += __shfl_xor(o, 32);
    if (half == 0) {
        float v = o / s;
        xout[(size_t)i * ostride + ocol0 + 32 * k + h] = v > 0.f ? v : 0.f;
    }
}

// -------- fused pooling + classifier: batch is SORTED -> binary search ------
__global__ __launch_bounds__(192) void pool_classify(
    const float* __restrict__ hbuf, const int* __restrict__ batch,
    const float* __restrict__ Wf, const float* __restrict__ bfb,
    float* __restrict__ out)
{
    __shared__ int bnd[2];
    __shared__ float pooled[192];
    __shared__ float z[10];
    __shared__ float red[2];
    int g = blockIdx.x, t = threadIdx.x;
    if (t == 0) {
        int lo = 0, hi = GN;
        while (lo < hi) { int mid = (lo + hi) >> 1; if (batch[mid] < g) lo = mid + 1; else hi = mid; }
        bnd[0] = lo;
        hi = GN;
        while (lo < hi) { int mid = (lo + hi) >> 1; if (batch[mid] < g + 1) lo = mid + 1; else hi = mid; }
        bnd[1] = lo;
    }
    __syncthreads();
    int s = bnd[0], e = bnd[1];
    float acc = 0.f;
    for (int n = s; n < e; ++n) acc += hbuf[(size_t)n * 192 + t];
    pooled[t] = (e > s) ? acc / (float)(e - s) : 0.f;
    __syncthreads();
    if (t < 10) {
        float zt = bfb[t];
        for (int c = 0; c < 192; ++c) zt += pooled[c] * Wf[c * 10 + t];
        z[t] = zt;
    }
    __syncthreads();
    if (t == 0) {
        float m = z[0];
        for (int o = 1; o < 10; ++o) m = fmaxf(m, z[o]);
        float ssum = 0.f;
        for (int o = 0; o < 10; ++o) ssum += __expf(z[o] - m);
        red[0] = m; red[1] = ssum;
    }
    __syncthreads();
    if (t < 10) out[g * 10 + t] = __expf(z[t] - red[0]) / red[1];
}

extern "C" void kernel_launch(void* const* d_in, const int* in_sizes, int n_in,
                              void* d_out, int out_size, void* d_ws, size_t ws_size,
                              hipStream_t stream)
{
    const float* x    = (const float*)d_in[0];
    const float* adj  = (const float*)d_in[1];
    const int*   batch= (const int*)d_in[2];
    const float* W1   = (const float*)d_in[3];
    const float* b1   = (const float*)d_in[4];
    const float* a1w1 = (const float*)d_in[5];
    const float* a1b1 = (const float*)d_in[6];
    const float* a2w1 = (const float*)d_in[7];
    const float* a2b1 = (const float*)d_in[8];
    const float* W2   = (const float*)d_in[9];
    const float* b2   = (const float*)d_in[10];
    const float* a1w2 = (const float*)d_in[11];
    const float* a1b2 = (const float*)d_in[12];
    const float* a2w2 = (const float*)d_in[13];
    const float* a2b2 = (const float*)d_in[14];
    const float* W3   = (const float*)d_in[15];
    const float* b3   = (const float*)d_in[16];
    const float* a1w3 = (const float*)d_in[17];
    const float* a1b3 = (const float*)d_in[18];
    const float* a2w3 = (const float*)d_in[19];
    const float* a2b3 = (const float*)d_in[20];
    const float* Wf   = (const float*)d_in[21];
    const float* bf   = (const float*)d_in[22];
    float* out = (float*)d_out;

    char* base = (char*)d_ws;
    int*   csr_cnt = (int*)(base + 0);            // 16 KiB
    float* s1      = (float*)(base + 16384);      // 32 KiB
    float* s2      = (float*)(base + 49152);      // 32 KiB
    float* fbuf    = (float*)(base + 81920);      // 1 MiB
    float* hbuf    = (float*)(base + 1130496);    // 3 MiB
    int*   csr_col = (int*)(base + 4276224);      // 8 MiB
    (void)ws_size; (void)n_in; (void)in_sizes; (void)out_size;

    build_csr<<<GN, 256, 0, stream>>>(adj, csr_cnt, csr_col);

    linear_scores<512><<<GN / 64, 256, 0, stream>>>(x, 512, W1, b1, a1w1, a1b1,
                                                    a2w1, a2b1, fbuf, s1, s2);
    attn_kernel<<<GN, 128, 0, stream>>>(fbuf, s1, s2, csr_cnt, csr_col, hbuf, 192, 0);

    linear_scores<64><<<GN / 64, 256, 0, stream>>>(hbuf, 192, W2, b2, a1w2, a1b2,
                                                   a2w2, a2b2, fbuf, s1, s2);
    attn_kernel<<<GN, 128, 0, stream>>>(fbuf, s1, s2, csr_cnt, csr_col, hbuf, 192, 64);

    linear_scores<64><<<GN / 64, 256, 0, stream>>>(hbuf + 64, 192, W3, b3, a1w3, a1b3,
                                                   a2w3, a2b3, fbuf, s1, s2);
    attn_kernel<<<GN, 128, 0, stream>>>(fbuf, s1, s2, csr_cnt, csr_col, hbuf, 192, 128);

    pool_classify<<<NGRAPH, 192, 0, stream>>>(hbuf, batch, Wf, bf, out);
}